// Round 5
// baseline (56.818 us; speedup 1.0000x reference)
//
#include <hip/hip_runtime.h>
#include <hip/hip_bf16.h>
#include <math.h>

#define NB 16384
#define ND 128
#define NH 512
#define NO 128
#define NE 8
#define CPAD 32
#define NCH 8                 // chunks of 64 h
#define EPSF 2.2204460492503131e-16f

using bf16x8 = __attribute__((ext_vector_type(8))) short;
using f32x16 = __attribute__((ext_vector_type(16))) float;
using uint2v = __attribute__((ext_vector_type(2))) unsigned;

// ---- workspace layout (bytes) ----
#define WS_COUNTS 0u                       // int  [NE*CPAD]
#define WS_IMP    1024u                    // float[NE*CPAD]
#define WS_TOKID  2048u                    // int  [NE][NB]  (tok | which<<30)
#define WS_TOKGG  526336u                  // float2[NB]
#define WS_XBF    657408u                  // ushort[NB][ND]
#define WS_W1F    4851712u                 // ushort, frag-linear w1 (1MB)
#define WS_W2F    5900288u                 // ushort, frag-linear w2 (1MB)
#define WS_YSTAGE 6948864u                 // float[NB][2][NO] (16.8MB)

__device__ __forceinline__ unsigned f2bf(float f){
  unsigned u = __float_as_uint(f);
  u += 0x7FFFu + ((u >> 16) & 1u);
  return u >> 16;
}
__device__ __forceinline__ unsigned cvtpk(float lo, float hi){
  unsigned r;
  asm("v_cvt_pk_bf16_f32 %0, %1, %2" : "=v"(r) : "v"(lo), "v"(hi));
  return r;
}
__device__ __forceinline__ void gld16(const void* g, void* l){
  __builtin_amdgcn_global_load_lds((const __attribute__((address_space(1))) void*)g,
                                   (__attribute__((address_space(3))) void*)l, 16, 0, 0);
}

// ============ prep: gating (blocks 0-255) + w1 frag-pack (256-511) + w2 frag-pack (512-767)
__global__ __launch_bounds__(256) void prep_kernel(
    const float* __restrict__ x, const float* __restrict__ wg,
    const float* __restrict__ w1, const float* __restrict__ w2,
    unsigned short* __restrict__ xbf, unsigned short* __restrict__ w1f,
    unsigned short* __restrict__ w2f, int* __restrict__ counts,
    float* __restrict__ imp, int* __restrict__ tok_ids, float2* __restrict__ tok_gg){
  int bx = blockIdx.x, tid = threadIdx.x;
  if (bx >= 512){            // ---- w2 pack: w2f[e][c][hb(8)][o(128)][8] <- w2[e][h][o]
    int u = (bx - 512)*256 + tid;
    int o = u & 127, hb = (u>>7)&7, c = (u>>10)&7, e = u>>13;
    int h0 = c*64 + (hb>>1)*16 + (hb&1)*8;
    const float* src = w2 + (size_t)e*NH*NO + (size_t)h0*NO + o;
    unsigned q[4];
    #pragma unroll
    for (int p = 0; p < 4; ++p)
      q[p] = f2bf(src[(2*p)*NO]) | (f2bf(src[(2*p+1)*NO]) << 16);
    *(uint4*)(w2f + (size_t)u*8) = make_uint4(q[0], q[1], q[2], q[3]);
    return;
  }
  if (bx >= 256){            // ---- w1 pack: w1f[e][c][hf(2)][db(16)][h32(32)][8] <- w1[e][d][h]
    int u = (bx - 256)*256 + tid;
    int h32 = u & 31, db = (u>>5)&15, hf = (u>>9)&1, c = (u>>10)&7, e = u>>13;
    int d0 = (db>>1)*16 + (db&1)*8;
    int hg = c*64 + hf*32 + h32;
    const float* src = w1 + (size_t)e*ND*NH + (size_t)d0*NH + hg;
    unsigned q[4];
    #pragma unroll
    for (int p = 0; p < 4; ++p)
      q[p] = f2bf(src[(2*p)*NH]) | (f2bf(src[(2*p+1)*NH]) << 16);
    *(uint4*)(w1f + (size_t)u*8) = make_uint4(q[0], q[1], q[2], q[3]);
    return;
  }
  // ---- gating: 64 tokens/block, 4 lanes per token, f64 logits
  __shared__ int   lcnt[NE];
  __shared__ float limp[NE];
  __shared__ int   lbase[NE];
  if (tid < NE){ lcnt[tid] = 0; limp[tid] = 0.f; }
  __syncthreads();
  int tok  = bx*64 + (tid >> 2);
  int part = tid & 3;
  const float4* xr4 = (const float4*)(x + (size_t)tok*ND);
  double acc[NE];
  #pragma unroll
  for (int e = 0; e < NE; ++e) acc[e] = 0.0;
  #pragma unroll
  for (int j = 0; j < 8; ++j){
    int f4 = part + j*4;
    float4 v = xr4[f4];
    uint2 p;
    p.x = f2bf(v.x) | (f2bf(v.y) << 16);
    p.y = f2bf(v.z) | (f2bf(v.w) << 16);
    *(uint2*)(xbf + (size_t)tok*ND + f4*4) = p;
    const float4* wr = (const float4*)(wg + f4*32);
    float vm[4] = {v.x, v.y, v.z, v.w};
    #pragma unroll
    for (int m = 0; m < 4; ++m){
      float4 wa = wr[2*m], wb = wr[2*m+1];
      double d = (double)vm[m];
      acc[0] += d*(double)wa.x; acc[1] += d*(double)wa.y;
      acc[2] += d*(double)wa.z; acc[3] += d*(double)wa.w;
      acc[4] += d*(double)wb.x; acc[5] += d*(double)wb.y;
      acc[6] += d*(double)wb.z; acc[7] += d*(double)wb.w;
    }
  }
  #pragma unroll
  for (int e = 0; e < NE; ++e){
    acc[e] += __shfl_xor(acc[e], 1);
    acc[e] += __shfl_xor(acc[e], 2);
  }
  int i0 = 0, i1 = 0, s0 = 0, s1 = 0;
  float g0 = 0.f, g1 = 0.f;
  if (part == 0){
    double l0 = acc[0];
    #pragma unroll
    for (int e = 1; e < NE; ++e) if (acc[e] > l0){ l0 = acc[e]; i0 = e; }
    i1 = (i0 == 0) ? 1 : 0;
    double l1 = acc[i1];
    #pragma unroll
    for (int e = 0; e < NE; ++e) if (e != i0 && acc[e] > l1){ l1 = acc[e]; i1 = e; }
    float e1 = expf((float)(l1 - l0));
    g0 = 1.0f/(1.0f + e1);
    g1 = e1/(1.0f + e1);
    s0 = atomicAdd(&lcnt[i0], 1);
    s1 = atomicAdd(&lcnt[i1], 1);
    atomicAdd(&limp[i0], g0);
    atomicAdd(&limp[i1], g1);
    tok_gg[tok] = make_float2(g0, g1);
  }
  __syncthreads();
  if (tid < NE){
    lbase[tid] = atomicAdd(&counts[tid*CPAD], lcnt[tid]);
    atomicAdd(&imp[tid*CPAD], limp[tid]);
  }
  __syncthreads();
  if (part == 0){
    tok_ids[i0*NB + lbase[i0] + s0] = tok;
    tok_ids[i1*NB + lbase[i1] + s1] = tok | (1 << 30);
  }
}

// ============ experts: 128 tok/block, 4 waves x 32-tok Mfrag, 32x32x16 MFMA,
// frag-linear LDS staging (conflict-free), ht kept in-register via cvt_pk+permlane32_swap.
__global__ __launch_bounds__(256) void expert_kernel(
    const unsigned short* __restrict__ xbf, const unsigned short* __restrict__ w1f,
    const unsigned short* __restrict__ w2f, const float* __restrict__ b1,
    const float* __restrict__ b2, const int* __restrict__ counts,
    const int* __restrict__ tok_ids, float* __restrict__ ystage){
  __shared__ char smem[65536];               // w1buf[2][16K] | w2buf[2][16K]
  int e = blockIdx.y;
  int n_e = counts[e*CPAD];
  int base = blockIdx.x*128;
  if (base >= n_e) return;
  int tid = threadIdx.x, wid = tid >> 6, lane = tid & 63, l31 = lane & 31, hi = lane >> 5;
  const int* tid_e = tok_ids + e*NB;
  char* w1buf = smem;
  char* w2buf = smem + 32768;
  const char* g1base = (const char*)w1f + ((size_t)e*NCH)*16384;
  const char* g2base = (const char*)w2f + ((size_t)e*NCH)*16384;

  int slot0 = base + wid*32 + l31;
  int raw0 = tid_e[slot0 < n_e ? slot0 : n_e-1];
  int tok0 = raw0 & 0x3FFFFFFF;
  bf16x8 xfrag[8];
  #pragma unroll
  for (int k = 0; k < 8; ++k)
    xfrag[k] = *(const bf16x8*)(xbf + (size_t)tok0*ND + (k*2 + hi)*8);

#define STAGE(c, bsel) do { \
    const char* _g1 = g1base + (size_t)(c)*16384 + wid*1024 + lane*16; \
    const char* _g2 = g2base + (size_t)(c)*16384 + wid*1024 + lane*16; \
    char* _l1 = w1buf + (bsel)*16384 + wid*1024; \
    char* _l2 = w2buf + (bsel)*16384 + wid*1024; \
    _Pragma("unroll") \
    for (int _s = 0; _s < 4; ++_s){ \
      gld16(_g1 + _s*4096, _l1 + _s*4096); \
      gld16(_g2 + _s*4096, _l2 + _s*4096); \
    } \
  } while(0)

  STAGE(0, 0);
  f32x16 yacc[4];
  #pragma unroll
  for (int ot = 0; ot < 4; ++ot)
    #pragma unroll
    for (int i = 0; i < 16; ++i) yacc[ot][i] = 0.f;
  __syncthreads();

  for (int c = 0; c < NCH; ++c){
    int b = c & 1;
    if (c + 1 < NCH) STAGE(c + 1, b ^ 1);
    bf16x8 aht[4];
    #pragma unroll
    for (int hf = 0; hf < 2; ++hf){
      f32x16 hacc;
      #pragma unroll
      for (int i = 0; i < 16; ++i) hacc[i] = 0.f;
      #pragma unroll
      for (int k = 0; k < 8; ++k){
        bf16x8 a = *(const bf16x8*)(w1buf + b*16384 + hf*8192 + (k*2 + hi)*512 + l31*16);
        hacc = __builtin_amdgcn_mfma_f32_32x32x16_bf16(a, xfrag[k], hacc, 0, 0, 0);
      }
      const float4* b1p = (const float4*)(b1 + e*NH + c*64 + hf*32 + hi*4);
      float dv[16];
      #pragma unroll
      for (int g = 0; g < 4; ++g){
        float4 bv = b1p[2*g];
        dv[4*g+0] = fmaxf(hacc[4*g+0] + bv.x, 0.f);
        dv[4*g+1] = fmaxf(hacc[4*g+1] + bv.y, 0.f);
        dv[4*g+2] = fmaxf(hacc[4*g+2] + bv.z, 0.f);
        dv[4*g+3] = fmaxf(hacc[4*g+3] + bv.w, 0.f);
      }
      unsigned A0 = cvtpk(dv[0], dv[1]),  A1 = cvtpk(dv[2], dv[3]);
      unsigned A2 = cvtpk(dv[4], dv[5]),  A3 = cvtpk(dv[6], dv[7]);
      unsigned A4 = cvtpk(dv[8], dv[9]),  A5 = cvtpk(dv[10], dv[11]);
      unsigned A6 = cvtpk(dv[12], dv[13]), A7 = cvtpk(dv[14], dv[15]);
      uint2v r0 = __builtin_amdgcn_permlane32_swap(A0, A2, false, false);
      uint2v r1 = __builtin_amdgcn_permlane32_swap(A1, A3, false, false);
      uint2v r2 = __builtin_amdgcn_permlane32_swap(A4, A6, false, false);
      uint2v r3 = __builtin_amdgcn_permlane32_swap(A5, A7, false, false);
      union { unsigned u[4]; bf16x8 v; } fa, fb;
      fa.u[0] = r0[0]; fa.u[1] = r1[0]; fa.u[2] = r0[1]; fa.u[3] = r1[1];
      fb.u[0] = r2[0]; fb.u[1] = r3[0]; fb.u[2] = r2[1]; fb.u[3] = r3[1];
      aht[hf*2 + 0] = fa.v;
      aht[hf*2 + 1] = fb.v;
    }
    #pragma unroll
    for (int ot = 0; ot < 4; ++ot)
      #pragma unroll
      for (int kk = 0; kk < 4; ++kk){
        bf16x8 bfr = *(const bf16x8*)(w2buf + b*16384 + (kk*2 + hi)*2048 + (ot*32 + l31)*16);
        yacc[ot] = __builtin_amdgcn_mfma_f32_32x32x16_bf16(aht[kk], bfr, yacc[ot], 0, 0, 0);
      }
    __syncthreads();
  }
#undef STAGE
  float b2v[4];
  #pragma unroll
  for (int ot = 0; ot < 4; ++ot) b2v[ot] = b2[e*NO + ot*32 + l31];
  #pragma unroll
  for (int r = 0; r < 16; ++r){
    int row = (r & 3) + 8*(r >> 2) + 4*hi;
    int slot = base + wid*32 + row;
    if (slot < n_e){
      int rw = tid_e[slot];
      int tk = rw & 0x3FFFFFFF, wh = (rw >> 30) & 1;
      float* dst = ystage + ((size_t)tk*2 + wh)*NO + l31;
      #pragma unroll
      for (int ot = 0; ot < 4; ++ot)
        dst[ot*32] = yacc[ot][r] + b2v[ot];
    }
  }
}

// ============ combine: y[tok] = g0*row0 + g1*row1, eps-fix; loss in block 0
__global__ __launch_bounds__(256) void combine_kernel(
    const float* __restrict__ ystage, const float2* __restrict__ tok_gg,
    const int* __restrict__ counts, const float* __restrict__ imp,
    float* __restrict__ y){
  if (blockIdx.x == 0 && threadIdx.x == 0){
    double si = 0, sqi = 0, sl = 0, sql = 0;
    for (int e = 0; e < NE; ++e){
      double a = imp[e*CPAD];
      double b = (double)counts[e*CPAD];
      si += a; sqi += a*a; sl += b; sql += b*b;
    }
    double mi = si/8.0, vi = (sqi - 8.0*mi*mi)/7.0;
    double ml = sl/8.0, vl = (sql - 8.0*ml*ml)/7.0;
    y[NB*NO] = (float)(vi/(mi*mi + 1e-10) + vl/(ml*ml + 1e-10));
  }
  int idx = blockIdx.x*256 + threadIdx.x;    // 524288 threads, 4 floats each
  int tk = idx >> 5, q = idx & 31;
  float2 gg = tok_gg[tk];
  float4 a = *(const float4*)(ystage + (size_t)tk*256 + q*4);
  float4 b = *(const float4*)(ystage + (size_t)tk*256 + 128 + q*4);
  float4 v;
  v.x = gg.x*a.x + gg.y*b.x;  v.x = (v.x == 0.f) ? EPSF : v.x;
  v.y = gg.x*a.y + gg.y*b.y;  v.y = (v.y == 0.f) ? EPSF : v.y;
  v.z = gg.x*a.z + gg.y*b.z;  v.z = (v.z == 0.f) ? EPSF : v.z;
  v.w = gg.x*a.w + gg.y*b.w;  v.w = (v.w == 0.f) ? EPSF : v.w;
  *(float4*)(y + (size_t)tk*128 + q*4) = v;
}

extern "C" void kernel_launch(void* const* d_in, const int* in_sizes, int n_in,
                              void* d_out, int out_size, void* d_ws, size_t ws_size,
                              hipStream_t stream){
  (void)in_sizes; (void)n_in; (void)out_size; (void)ws_size;
  const float* x  = (const float*)d_in[0];
  const float* wg = (const float*)d_in[1];
  const float* w1 = (const float*)d_in[2];
  const float* b1 = (const float*)d_in[3];
  const float* w2 = (const float*)d_in[4];
  const float* b2 = (const float*)d_in[5];
  float* out = (float*)d_out;
  char* ws = (char*)d_ws;
  int*            counts  = (int*)(ws + WS_COUNTS);
  float*          imp     = (float*)(ws + WS_IMP);
  int*            tok_ids = (int*)(ws + WS_TOKID);
  float2*         tok_gg  = (float2*)(ws + WS_TOKGG);
  unsigned short* xbf     = (unsigned short*)(ws + WS_XBF);
  unsigned short* w1f     = (unsigned short*)(ws + WS_W1F);
  unsigned short* w2f     = (unsigned short*)(ws + WS_W2F);
  float*          ystage  = (float*)(ws + WS_YSTAGE);

  hipMemsetAsync(d_ws, 0, 2048, stream);
  prep_kernel<<<768, 256, 0, stream>>>(x, wg, w1, w2, xbf, w1f, w2f,
                                       counts, imp, tok_ids, tok_gg);
  expert_kernel<<<dim3(128, NE), 256, 0, stream>>>(xbf, w1f, w2f, b1, b2,
                                                   counts, tok_ids, ystage);
  combine_kernel<<<2048, 256, 0, stream>>>(ystage, tok_gg, counts, imp, out);
}

// Round 6
// 55.123 us; speedup vs baseline: 1.0307x; 1.0307x over previous
//
#include <hip/hip_runtime.h>
#include <hip/hip_bf16.h>
#include <math.h>

#define NB 16384
#define ND 128
#define NH 512
#define NO 128
#define NE 8
#define CPAD 32
#define NCH 16                // chunks of 32 h
#define EPSF 2.2204460492503131e-16f

using bf16x8 = __attribute__((ext_vector_type(8))) short;
using f32x16 = __attribute__((ext_vector_type(16))) float;
using uint2v = __attribute__((ext_vector_type(2))) unsigned;

// ---- workspace layout (bytes) ----
#define WS_COUNTS 0u                       // int  [NE*CPAD]
#define WS_IMP    1024u                    // float[NE*CPAD]
#define WS_TOKID  2048u                    // int  [NE][NB]  (tok | which<<30)
#define WS_TOKGG  526336u                  // float2[NB]
#define WS_XBF    657408u                  // ushort[NB][ND]
#define WS_W1F    4851712u                 // ushort, frag-linear w1 (1MB)
#define WS_W2F    5900288u                 // ushort, frag-linear w2 (1MB)
#define WS_YSTAGE 6948864u                 // ushort[NB][2][NO] bf16, gate-prescaled (8.4MB)

__device__ __forceinline__ unsigned f2bf(float f){
  unsigned u = __float_as_uint(f);
  u += 0x7FFFu + ((u >> 16) & 1u);
  return u >> 16;
}
__device__ __forceinline__ unsigned cvtpk(float lo, float hi){
  unsigned r;
  asm("v_cvt_pk_bf16_f32 %0, %1, %2" : "=v"(r) : "v"(lo), "v"(hi));
  return r;
}
__device__ __forceinline__ void gld16(const void* g, void* l){
  __builtin_amdgcn_global_load_lds((const __attribute__((address_space(1))) void*)g,
                                   (__attribute__((address_space(3))) void*)l, 16, 0, 0);
}

// ============ prep: gating (blocks 0-255) + w1 frag-pack (256-511) + w2 frag-pack (512-767)
__global__ __launch_bounds__(256) void prep_kernel(
    const float* __restrict__ x, const float* __restrict__ wg,
    const float* __restrict__ w1, const float* __restrict__ w2,
    unsigned short* __restrict__ xbf, unsigned short* __restrict__ w1f,
    unsigned short* __restrict__ w2f, int* __restrict__ counts,
    float* __restrict__ imp, int* __restrict__ tok_ids, float2* __restrict__ tok_gg){
  int bx = blockIdx.x, tid = threadIdx.x;
  if (bx >= 512){            // ---- w2 pack: w2f[e][c32(16)][hb(4)][o(128)][8h] <- w2[e][h][o]
    int u = (bx - 512)*256 + tid;
    int o = u & 127, hb = (u>>7)&3, c = (u>>9)&15, e = u>>13;
    int h0 = c*32 + (hb>>1)*16 + (hb&1)*8;
    const float* src = w2 + (size_t)e*NH*NO + (size_t)h0*NO + o;
    unsigned q[4];
    #pragma unroll
    for (int p = 0; p < 4; ++p)
      q[p] = f2bf(src[(2*p)*NO]) | (f2bf(src[(2*p+1)*NO]) << 16);
    *(uint4*)(w2f + (size_t)u*8) = make_uint4(q[0], q[1], q[2], q[3]);
    return;
  }
  if (bx >= 256){            // ---- w1 pack: w1f[e][c32(16)][db(16)][h32(32)][8d] <- w1[e][d][h]
    int u = (bx - 256)*256 + tid;
    int h32 = u & 31, db = (u>>5)&15, c = (u>>9)&15, e = u>>13;
    int d0 = (db>>1)*16 + (db&1)*8;
    int hg = c*32 + h32;
    const float* src = w1 + (size_t)e*ND*NH + (size_t)d0*NH + hg;
    unsigned q[4];
    #pragma unroll
    for (int p = 0; p < 4; ++p)
      q[p] = f2bf(src[(2*p)*NH]) | (f2bf(src[(2*p+1)*NH]) << 16);
    *(uint4*)(w1f + (size_t)u*8) = make_uint4(q[0], q[1], q[2], q[3]);
    return;
  }
  // ---- gating: 64 tokens/block, 4 lanes per token, f64 logits
  __shared__ int   lcnt[NE];
  __shared__ float limp[NE];
  __shared__ int   lbase[NE];
  if (tid < NE){ lcnt[tid] = 0; limp[tid] = 0.f; }
  __syncthreads();
  int tok  = bx*64 + (tid >> 2);
  int part = tid & 3;
  const float4* xr4 = (const float4*)(x + (size_t)tok*ND);
  double acc[NE];
  #pragma unroll
  for (int e = 0; e < NE; ++e) acc[e] = 0.0;
  #pragma unroll
  for (int j = 0; j < 8; ++j){
    int f4 = part + j*4;
    float4 v = xr4[f4];
    uint2 p;
    p.x = f2bf(v.x) | (f2bf(v.y) << 16);
    p.y = f2bf(v.z) | (f2bf(v.w) << 16);
    *(uint2*)(xbf + (size_t)tok*ND + f4*4) = p;
    const float4* wr = (const float4*)(wg + f4*32);
    float vm[4] = {v.x, v.y, v.z, v.w};
    #pragma unroll
    for (int m = 0; m < 4; ++m){
      float4 wa = wr[2*m], wb = wr[2*m+1];
      double d = (double)vm[m];
      acc[0] += d*(double)wa.x; acc[1] += d*(double)wa.y;
      acc[2] += d*(double)wa.z; acc[3] += d*(double)wa.w;
      acc[4] += d*(double)wb.x; acc[5] += d*(double)wb.y;
      acc[6] += d*(double)wb.z; acc[7] += d*(double)wb.w;
    }
  }
  #pragma unroll
  for (int e = 0; e < NE; ++e){
    acc[e] += __shfl_xor(acc[e], 1);
    acc[e] += __shfl_xor(acc[e], 2);
  }
  int i0 = 0, i1 = 0, s0 = 0, s1 = 0;
  float g0 = 0.f, g1 = 0.f;
  if (part == 0){
    double l0 = acc[0];
    #pragma unroll
    for (int e = 1; e < NE; ++e) if (acc[e] > l0){ l0 = acc[e]; i0 = e; }
    i1 = (i0 == 0) ? 1 : 0;
    double l1 = acc[i1];
    #pragma unroll
    for (int e = 0; e < NE; ++e) if (e != i0 && acc[e] > l1){ l1 = acc[e]; i1 = e; }
    float e1 = expf((float)(l1 - l0));
    g0 = 1.0f/(1.0f + e1);
    g1 = e1/(1.0f + e1);
    s0 = atomicAdd(&lcnt[i0], 1);
    s1 = atomicAdd(&lcnt[i1], 1);
    atomicAdd(&limp[i0], g0);
    atomicAdd(&limp[i1], g1);
    tok_gg[tok] = make_float2(g0, g1);
  }
  __syncthreads();
  if (tid < NE){
    lbase[tid] = atomicAdd(&counts[tid*CPAD], lcnt[tid]);
    atomicAdd(&imp[tid*CPAD], limp[tid]);
  }
  __syncthreads();
  if (part == 0){
    tok_ids[i0*NB + lbase[i0] + s0] = tok;
    tok_ids[i1*NB + lbase[i1] + s1] = tok | (1 << 30);
  }
}

// ============ experts: compact 1D grid, runtime (e,base) mapping; 128 tok/block,
// 4 waves x 32-tok Mfrag, 32x32x16 MFMA, 32-h double-buffered chunks (32KB LDS).
__global__ __launch_bounds__(256) void expert_kernel(
    const unsigned short* __restrict__ xbf, const unsigned short* __restrict__ w1f,
    const unsigned short* __restrict__ w2f, const float* __restrict__ b1,
    const float* __restrict__ b2, const int* __restrict__ counts,
    const int* __restrict__ tok_ids, const float2* __restrict__ tok_gg,
    unsigned short* __restrict__ ystage){
  __shared__ char smem[32768];               // w1buf[2][8K] | w2buf[2][8K]
  // map compact block id -> (expert, base)
  int b = blockIdx.x;
  int e = 0, base = 0, accb = 0, n_e = 0;
  #pragma unroll
  for (int ee = 0; ee < NE; ++ee){
    int ne = counts[ee*CPAD];
    int nbl = (ne + 127) >> 7;
    if (e == 0 && base == 0 && b < accb + nbl && n_e == 0){
      e = ee; base = (b - accb)*128; n_e = ne;
    }
    accb += nbl;
  }
  if (b >= accb) return;
  if (n_e == 0) return;
  int tid = threadIdx.x, wid = tid >> 6, lane = tid & 63, l31 = lane & 31, hi = lane >> 5;
  const int* tid_e = tok_ids + e*NB;
  char* w1buf = smem;
  char* w2buf = smem + 16384;
  const char* g1base = (const char*)w1f + ((size_t)e*NCH)*8192;
  const char* g2base = (const char*)w2f + ((size_t)e*NCH)*8192;

  int slot0 = base + wid*32 + l31;
  int raw0 = tid_e[slot0 < n_e ? slot0 : n_e-1];
  int tok0 = raw0 & 0x3FFFFFFF;
  bf16x8 xfrag[8];
  #pragma unroll
  for (int k = 0; k < 8; ++k)
    xfrag[k] = *(const bf16x8*)(xbf + (size_t)tok0*ND + (k*2 + hi)*8);

#define STAGE(c, bsel) do { \
    const char* _g1 = g1base + (size_t)(c)*8192 + wid*1024 + lane*16; \
    const char* _g2 = g2base + (size_t)(c)*8192 + wid*1024 + lane*16; \
    char* _l1 = w1buf + (bsel)*8192 + wid*1024; \
    char* _l2 = w2buf + (bsel)*8192 + wid*1024; \
    _Pragma("unroll") \
    for (int _s = 0; _s < 2; ++_s){ \
      gld16(_g1 + _s*4096, _l1 + _s*4096); \
      gld16(_g2 + _s*4096, _l2 + _s*4096); \
    } \
  } while(0)

  STAGE(0, 0);
  f32x16 yacc[4];
  #pragma unroll
  for (int ot = 0; ot < 4; ++ot)
    #pragma unroll
    for (int i = 0; i < 16; ++i) yacc[ot][i] = 0.f;
  __syncthreads();

  for (int c = 0; c < NCH; ++c){
    int bb = c & 1;
    if (c + 1 < NCH) STAGE(c + 1, bb ^ 1);
    // stage 1: h^T[32h x 32tok] for this 32-h chunk
    f32x16 hacc;
    #pragma unroll
    for (int i = 0; i < 16; ++i) hacc[i] = 0.f;
    #pragma unroll
    for (int k = 0; k < 8; ++k){
      bf16x8 a = *(const bf16x8*)(w1buf + bb*8192 + (k*2 + hi)*512 + l31*16);
      hacc = __builtin_amdgcn_mfma_f32_32x32x16_bf16(a, xfrag[k], hacc, 0, 0, 0);
    }
    const float4* b1p = (const float4*)(b1 + e*NH + c*32 + hi*4);
    float dv[16];
    #pragma unroll
    for (int g = 0; g < 4; ++g){
      float4 bv = b1p[2*g];
      dv[4*g+0] = fmaxf(hacc[4*g+0] + bv.x, 0.f);
      dv[4*g+1] = fmaxf(hacc[4*g+1] + bv.y, 0.f);
      dv[4*g+2] = fmaxf(hacc[4*g+2] + bv.z, 0.f);
      dv[4*g+3] = fmaxf(hacc[4*g+3] + bv.w, 0.f);
    }
    unsigned A0 = cvtpk(dv[0], dv[1]),  A1 = cvtpk(dv[2], dv[3]);
    unsigned A2 = cvtpk(dv[4], dv[5]),  A3 = cvtpk(dv[6], dv[7]);
    unsigned A4 = cvtpk(dv[8], dv[9]),  A5 = cvtpk(dv[10], dv[11]);
    unsigned A6 = cvtpk(dv[12], dv[13]), A7 = cvtpk(dv[14], dv[15]);
    uint2v r0 = __builtin_amdgcn_permlane32_swap(A0, A2, false, false);
    uint2v r1 = __builtin_amdgcn_permlane32_swap(A1, A3, false, false);
    uint2v r2 = __builtin_amdgcn_permlane32_swap(A4, A6, false, false);
    uint2v r3 = __builtin_amdgcn_permlane32_swap(A5, A7, false, false);
    union { unsigned u[4]; bf16x8 v; } fa, fb;
    fa.u[0] = r0[0]; fa.u[1] = r1[0]; fa.u[2] = r0[1]; fa.u[3] = r1[1];
    fb.u[0] = r2[0]; fb.u[1] = r3[0]; fb.u[2] = r2[1]; fb.u[3] = r3[1];
    bf16x8 aht0 = fa.v, aht1 = fb.v;
    // stage 2: y += relu(h) @ w2 for this 32-h chunk (kk = 2 k-frags)
    #pragma unroll
    for (int ot = 0; ot < 4; ++ot){
      bf16x8 bf0 = *(const bf16x8*)(w2buf + bb*8192 + (0*2 + hi)*2048 + (ot*32 + l31)*16);
      yacc[ot] = __builtin_amdgcn_mfma_f32_32x32x16_bf16(aht0, bf0, yacc[ot], 0, 0, 0);
      bf16x8 bf1 = *(const bf16x8*)(w2buf + bb*8192 + (1*2 + hi)*2048 + (ot*32 + l31)*16);
      yacc[ot] = __builtin_amdgcn_mfma_f32_32x32x16_bf16(aht1, bf1, yacc[ot], 0, 0, 0);
    }
    __syncthreads();
  }
#undef STAGE
  float b2v[4];
  #pragma unroll
  for (int ot = 0; ot < 4; ++ot) b2v[ot] = b2[e*NO + ot*32 + l31];
  #pragma unroll
  for (int r = 0; r < 16; ++r){
    int row = (r & 3) + 8*(r >> 2) + 4*hi;
    int slot = base + wid*32 + row;
    if (slot < n_e){
      int rw = tid_e[slot];
      int tk = rw & 0x3FFFFFFF, wh = (rw >> 30) & 1;
      float2 gg = tok_gg[tk];
      float g = wh ? gg.y : gg.x;
      unsigned short* dst = ystage + ((size_t)tk*2 + wh)*NO + l31;
      #pragma unroll
      for (int ot = 0; ot < 4; ++ot)
        dst[ot*32] = (unsigned short)f2bf((yacc[ot][r] + b2v[ot]) * g);
    }
  }
}

// ============ combine: y[tok] = row0 + row1 (already gate-scaled bf16), eps-fix; loss in block 0
__global__ __launch_bounds__(256) void combine_kernel(
    const unsigned short* __restrict__ ystage, const int* __restrict__ counts,
    const float* __restrict__ imp, float* __restrict__ y){
  if (blockIdx.x == 0 && threadIdx.x == 0){
    double si = 0, sqi = 0, sl = 0, sql = 0;
    for (int e = 0; e < NE; ++e){
      double a = imp[e*CPAD];
      double b = (double)counts[e*CPAD];
      si += a; sqi += a*a; sl += b; sql += b*b;
    }
    double mi = si/8.0, vi = (sqi - 8.0*mi*mi)/7.0;
    double ml = sl/8.0, vl = (sql - 8.0*ml*ml)/7.0;
    y[NB*NO] = (float)(vi/(mi*mi + 1e-10) + vl/(ml*ml + 1e-10));
  }
  int idx = blockIdx.x*256 + threadIdx.x;    // 262144 threads, 8 outs each
  int tk = idx >> 4, q = idx & 15;
  const unsigned short* r0 = ystage + (size_t)tk*256 + q*8;
  uint4 a = *(const uint4*)r0;
  uint4 bq = *(const uint4*)(r0 + 128);
  unsigned aw[4] = {a.x, a.y, a.z, a.w};
  unsigned bw[4] = {bq.x, bq.y, bq.z, bq.w};
  float4 o0, o1;
  float* op[8] = {&o0.x,&o0.y,&o0.z,&o0.w,&o1.x,&o1.y,&o1.z,&o1.w};
  #pragma unroll
  for (int i = 0; i < 4; ++i){
    float vlo = __uint_as_float(aw[i] << 16)        + __uint_as_float(bw[i] << 16);
    float vhi = __uint_as_float(aw[i] & 0xFFFF0000u) + __uint_as_float(bw[i] & 0xFFFF0000u);
    *op[2*i]   = (vlo == 0.f) ? EPSF : vlo;
    *op[2*i+1] = (vhi == 0.f) ? EPSF : vhi;
  }
  float* dst = y + (size_t)tk*128 + q*8;
  *(float4*)dst     = o0;
  *(float4*)(dst+4) = o1;
}

extern "C" void kernel_launch(void* const* d_in, const int* in_sizes, int n_in,
                              void* d_out, int out_size, void* d_ws, size_t ws_size,
                              hipStream_t stream){
  (void)in_sizes; (void)n_in; (void)out_size; (void)ws_size;
  const float* x  = (const float*)d_in[0];
  const float* wg = (const float*)d_in[1];
  const float* w1 = (const float*)d_in[2];
  const float* b1 = (const float*)d_in[3];
  const float* w2 = (const float*)d_in[4];
  const float* b2 = (const float*)d_in[5];
  float* out = (float*)d_out;
  char* ws = (char*)d_ws;
  int*            counts  = (int*)(ws + WS_COUNTS);
  float*          imp     = (float*)(ws + WS_IMP);
  int*            tok_ids = (int*)(ws + WS_TOKID);
  float2*         tok_gg  = (float2*)(ws + WS_TOKGG);
  unsigned short* xbf     = (unsigned short*)(ws + WS_XBF);
  unsigned short* w1f     = (unsigned short*)(ws + WS_W1F);
  unsigned short* w2f     = (unsigned short*)(ws + WS_W2F);
  unsigned short* ystage  = (unsigned short*)(ws + WS_YSTAGE);

  hipMemsetAsync(d_ws, 0, 2048, stream);
  prep_kernel<<<768, 256, 0, stream>>>(x, wg, w1, w2, xbf, w1f, w2f,
                                       counts, imp, tok_ids, tok_gg);
  expert_kernel<<<264, 256, 0, stream>>>(xbf, w1f, w2f, b1, b2,
                                         counts, tok_ids, tok_gg, ystage);
  combine_kernel<<<1024, 256, 0, stream>>>(ystage, counts, imp, out);
}